// Round 1
// baseline (309.197 us; speedup 1.0000x reference)
//
#include <hip/hip_runtime.h>

#define T_LEN   524288
#define BATCH   32
#define WIN     1024
#define STRIDE  256
#define NCODE   32
#define NFRAMES 2049                 // T_LEN/STRIDE + 1
#define FPB     8                    // frames per block in autocorr kernel
#define SPAN    ((FPB - 1) * STRIDE + WIN)   // 2816 floats staged per block

// ---------------------------------------------------------------------------
// Kernel 1: per-frame circular autocorrelation, lags 0..32.
// corr[b,f,k] = sum_{n=0}^{1023} x[n] * x[(n+k) & 1023],  x = padded[b, f*256 + .]
// One block = 256 threads = 4 waves; block covers 8 consecutive frames of one
// batch row (span 2816 floats staged in LDS). Each wave computes 2 frames:
// lane l accumulates 33 lag partials over samples 16l..16l+15 (circular reads
// from LDS into 48 registers), then 6-level __shfl_xor butterfly reduce.
// ---------------------------------------------------------------------------
__global__ __launch_bounds__(256) void autocorr_kernel(const float* __restrict__ in,
                                                       float* __restrict__ corr_ws) {
    __shared__ float stage[SPAN];
    const int b   = blockIdx.y;
    const int f0  = blockIdx.x * FPB;
    const int tid = threadIdx.x;
    const long base = (long)f0 * STRIDE;
    const float* row = in + (size_t)b * T_LEN;

    // Stage SPAN floats, coalesced float4, zero-fill past T (the w-pad).
    for (int c = tid; c < SPAN / 4; c += 256) {
        const int s = 4 * c;
        float4 v = make_float4(0.f, 0.f, 0.f, 0.f);
        const long g = base + s;                 // g and T_LEN are multiples of 4
        if (g < T_LEN) v = *reinterpret_cast<const float4*>(row + g);
        *reinterpret_cast<float4*>(&stage[s]) = v;
    }
    __syncthreads();

    const int wid = tid >> 6, lane = tid & 63;
    for (int rep = 0; rep < 2; ++rep) {
        const int fi = wid * 2 + rep;
        const int f  = f0 + fi;
        if (f >= NFRAMES) continue;              // no __syncthreads below: safe
        const int foff = fi * STRIDE;

        // 48 circularly-indexed samples per lane (12x ds_read_b128).
        float v[48];
        #pragma unroll
        for (int i = 0; i < 12; ++i) {
            const int off = (lane * 16 + i * 4) & (WIN - 1);   // multiple of 4
            const float4 q = *reinterpret_cast<const float4*>(&stage[foff + off]);
            v[4 * i + 0] = q.x; v[4 * i + 1] = q.y;
            v[4 * i + 2] = q.z; v[4 * i + 3] = q.w;
        }

        // 33 lag partial sums over this lane's 16 base samples.
        float p[NCODE + 1];
        #pragma unroll
        for (int k = 0; k <= NCODE; ++k) {
            float acc = 0.f;
            #pragma unroll
            for (int j = 0; j < 16; ++j) acc = fmaf(v[j], v[j + k], acc);
            p[k] = acc;
        }

        // Wave butterfly reduce (all 64 lanes end with the full sums).
        #pragma unroll
        for (int off = 32; off >= 1; off >>= 1) {
            #pragma unroll
            for (int k = 0; k <= NCODE; ++k)
                p[k] += __shfl_xor(p[k], off, 64);
        }

        if (lane == 0) {
            float* dst = corr_ws + ((size_t)b * NFRAMES + f) * (NCODE + 1);
            #pragma unroll
            for (int k = 0; k <= NCODE; ++k) dst[k] = p[k];
        }
    }
}

// ---------------------------------------------------------------------------
// Kernel 2: Levinson-Durbin, one thread per frame, fully unrolled so every
// array index is compile-time constant (registers, no scratch).
// Mirrors the reference _solve_toeplitz exactly (incl. eps clamps).
// ---------------------------------------------------------------------------
__global__ __launch_bounds__(256) void levinson_kernel(const float* __restrict__ corr_ws,
                                                       float* __restrict__ out) {
    const int t = blockIdx.x * 256 + threadIdx.x;
    if (t >= BATCH * NFRAMES) return;

    const float* c = corr_ws + (size_t)t * (NCODE + 1);
    float corr[NCODE + 1];
    #pragma unroll
    for (int i = 0; i <= NCODE; ++i) corr[i] = c[i];

    const float eps = 1e-7f;
    float sol[NCODE + 1];
    const float c0 = fmaxf(corr[0], eps);
    sol[0] = 1.0f;
    sol[1] = -corr[1] / c0;
    float extra = fmaf(corr[1], sol[1], corr[0]);

    #pragma unroll
    for (int k = 1; k < NCODE; ++k) {
        // lam = -(sol . flip(corr[1:k+2])) / max(extra, eps)
        float dot = 0.f;
        #pragma unroll
        for (int i = 0; i <= k; ++i) dot = fmaf(sol[i], corr[k + 1 - i], dot);
        const float lam = -dot / fmaxf(extra, eps);

        // sol_new[j] = aug[j] + lam * aug[k+1-j], aug = [sol(0..k), 0]
        float ns[NCODE + 1];
        #pragma unroll
        for (int j = 0; j <= k + 1; ++j) {
            const float a   = (j <= k) ? sol[j] : 0.f;
            const float rev = (j >= 1) ? sol[k + 1 - j] : 0.f;  // j==0 -> aug[k+1]==0
            ns[j] = fmaf(lam, rev, a);
        }
        #pragma unroll
        for (int j = 0; j <= k + 1; ++j) sol[j] = ns[j];

        extra = (1.f - lam * lam) * extra;
    }

    float* o = out + (size_t)t * NCODE;
    #pragma unroll
    for (int i = 0; i < NCODE; ++i) o[i] = sol[i + 1];
}

// ---------------------------------------------------------------------------
extern "C" void kernel_launch(void* const* d_in, const int* in_sizes, int n_in,
                              void* d_out, int out_size, void* d_ws, size_t ws_size,
                              hipStream_t stream) {
    const float* in  = (const float*)d_in[0];
    float* out       = (float*)d_out;
    float* corr_ws   = (float*)d_ws;   // needs 32*2049*33*4 B ~= 8.7 MB

    dim3 g1((NFRAMES + FPB - 1) / FPB, BATCH);
    autocorr_kernel<<<g1, 256, 0, stream>>>(in, corr_ws);

    const int total = BATCH * NFRAMES;
    levinson_kernel<<<(total + 255) / 256, 256, 0, stream>>>(corr_ws, out);
}

// Round 2
// 96.363 us; speedup vs baseline: 3.2087x; 3.2087x over previous
//
#include <hip/hip_runtime.h>

#define T_LEN   524288
#define BATCH   32
#define WIN     1024
#define STRIDE  256
#define NCODE   32
#define NFRAMES 2049                 // T_LEN/STRIDE + 1
#define NFR_TOT (BATCH * NFRAMES)    // 65568 frames

// ---------------------------------------------------------------------------
// Fused LPC: 4 lanes per frame (one 256-sample quarter each), circular
// autocorrelation lags 0..32 accumulated in registers from global memory
// (no LDS -> no bank conflicts), 2-level shfl_xor group reduce, then
// Levinson-Durbin fully unrolled in lane s==0, packed float4 output.
// ---------------------------------------------------------------------------
__global__ __launch_bounds__(256) void lpc_fused(const float* __restrict__ in,
                                                 float* __restrict__ out) {
    const int tid   = blockIdx.x * 256 + threadIdx.x;
    const int frame = tid >> 2;          // 4 lanes per frame
    const int s     = tid & 3;           // quarter index 0..3
    if (frame >= NFR_TOT) return;

    const int b      = frame / NFRAMES;
    const int f      = frame - b * NFRAMES;
    const float* row = in + (size_t)b * T_LEN;
    const int rowoff = f * STRIDE;       // frame start within the batch row

    // Guarded circular load of 4 floats at quarter-local index jp (mult of 4).
    // Window index (s*256+jp) & 1023 stays 16B-aligned; reads past T are the
    // reference's zero-pad. A float4 never straddles T_LEN (both mult of 4).
    auto ld4 = [&](int jp, float* dst) {
        const int pos = rowoff + ((s * 256 + jp) & (WIN - 1));
        float4 v = make_float4(0.f, 0.f, 0.f, 0.f);
        if (pos < T_LEN) v = *reinterpret_cast<const float4*>(row + pos);
        dst[0] = v.x; dst[1] = v.y; dst[2] = v.z; dst[3] = v.w;
    };

    float w[64], nw[32], acc[NCODE + 1];
    #pragma unroll
    for (int k = 0; k <= NCODE; ++k) acc[k] = 0.f;

    // w[j] = v[c*32 + j], v[j'] = x[rowoff + ((s*256 + j') & 1023)]
    #pragma unroll
    for (int i = 0; i < 16; ++i) ld4(i * 4, &w[i * 4]);

    #pragma unroll 1                     // keep body ~1.1K instr (I-cache)
    for (int c = 0; c < 8; ++c) {
        if (c < 7) {                     // prefetch next 32 lookahead floats
            #pragma unroll
            for (int i = 0; i < 8; ++i) ld4(c * 32 + 64 + i * 4, &nw[i * 4]);
        }
        // acc[k] += sum_{j<32} v[c*32+j] * v[c*32+j+k]   (j+k <= 63)
        #pragma unroll
        for (int k = 0; k <= NCODE; ++k) {
            float a = acc[k];
            #pragma unroll
            for (int j = 0; j < 32; ++j) a = fmaf(w[j], w[j + k], a);
            acc[k] = a;
        }
        #pragma unroll
        for (int j = 0; j < 32; ++j) w[j] = w[j + 32];
        if (c < 7) {
            #pragma unroll
            for (int j = 0; j < 32; ++j) w[j + 32] = nw[j];
        }
    }

    // Reduce the 4 quarter-partials (lanes 4g..4g+3); all 4 end with full sums.
    #pragma unroll
    for (int k = 0; k <= NCODE; ++k) {
        acc[k] += __shfl_xor(acc[k], 1, 64);
        acc[k] += __shfl_xor(acc[k], 2, 64);
    }

    if (s == 0) {
        // Levinson-Durbin, fully unrolled (static indices -> registers).
        const float eps = 1e-7f;
        float sol[NCODE + 1];
        const float c0 = fmaxf(acc[0], eps);
        sol[0] = 1.0f;
        sol[1] = -acc[1] / c0;
        float extra = fmaf(acc[1], sol[1], acc[0]);

        #pragma unroll
        for (int k = 1; k < NCODE; ++k) {
            float dot = 0.f;
            #pragma unroll
            for (int i = 0; i <= k; ++i) dot = fmaf(sol[i], acc[k + 1 - i], dot);
            const float lam = -dot / fmaxf(extra, eps);

            float ns[NCODE + 1];
            #pragma unroll
            for (int j = 0; j <= k + 1; ++j) {
                const float a   = (j <= k) ? sol[j] : 0.f;
                const float rev = (j >= 1) ? sol[k + 1 - j] : 0.f;
                ns[j] = fmaf(lam, rev, a);
            }
            #pragma unroll
            for (int j = 0; j <= k + 1; ++j) sol[j] = ns[j];

            extra = (1.f - lam * lam) * extra;
        }

        // 8 packed stores, 16 groups/wave -> 2KB contiguous per wave.
        float* o = out + (size_t)frame * NCODE;
        #pragma unroll
        for (int i = 0; i < 8; ++i) {
            *reinterpret_cast<float4*>(o + 4 * i) =
                make_float4(sol[4 * i + 1], sol[4 * i + 2],
                            sol[4 * i + 3], sol[4 * i + 4]);
        }
    }
}

// ---------------------------------------------------------------------------
extern "C" void kernel_launch(void* const* d_in, const int* in_sizes, int n_in,
                              void* d_out, int out_size, void* d_ws, size_t ws_size,
                              hipStream_t stream) {
    const float* in = (const float*)d_in[0];
    float* out      = (float*)d_out;

    const int total_threads = NFR_TOT * 4;
    const int blocks = (total_threads + 255) / 256;   // 1025
    lpc_fused<<<blocks, 256, 0, stream>>>(in, out);
}

// Round 3
// 41.809 us; speedup vs baseline: 7.3955x; 2.3049x over previous
//
#include <hip/hip_runtime.h>

#define T_LEN   524288
#define BATCH   32
#define WIN     1024
#define STRIDE  256
#define NCODE   32
#define NFRAMES 2049                 // T_LEN/STRIDE + 1
#define NFR_TOT (BATCH * NFRAMES)    // 65568 frames
#define NBLK    2048                 // 256-sample product-blocks per row
#define NG      (BATCH * NBLK)       // 65536 block-product groups

// ---------------------------------------------------------------------------
// Pass 1: lag-block products  B[k][b*2048+i] = sum_{m=256i}^{256i+255} x[b,m]*x[b,m+k]
// 4 lanes per x-block; lane s owns 64 samples + 32 lookahead (96 floats, all
// static register indices, no shifting). 2112 fully-unrolled FMAs per lane,
// then a 2-level shfl_xor group reduce. Only (i==2047, s==3) touches the
// zero-pad -> cheap guarded path for that one lane class.
// ---------------------------------------------------------------------------
__global__ __launch_bounds__(256) void blockprod_kernel(const float* __restrict__ in,
                                                        float* __restrict__ B) {
    const int tid = blockIdx.x * 256 + threadIdx.x;
    const int g   = tid >> 2;            // (b, i) group
    const int s   = tid & 3;
    const int b   = g >> 11;             // NBLK = 2048
    const int i   = g & (NBLK - 1);
    const float* row = in + (size_t)b * T_LEN;
    const int m0 = i * 256 + s * 64;     // reads [m0, m0+96)

    float w[96];
    if (m0 + 96 <= T_LEN) {
        #pragma unroll
        for (int q = 0; q < 24; ++q) {
            const float4 v = *reinterpret_cast<const float4*>(row + m0 + 4 * q);
            w[4*q] = v.x; w[4*q+1] = v.y; w[4*q+2] = v.z; w[4*q+3] = v.w;
        }
    } else {                             // last block's last lane: pad with 0
        #pragma unroll
        for (int q = 0; q < 24; ++q) {
            const int p = m0 + 4 * q;
            float4 v = make_float4(0.f, 0.f, 0.f, 0.f);
            if (p < T_LEN) v = *reinterpret_cast<const float4*>(row + p);
            w[4*q] = v.x; w[4*q+1] = v.y; w[4*q+2] = v.z; w[4*q+3] = v.w;
        }
    }

    float acc[NCODE + 1];
    #pragma unroll
    for (int k = 0; k <= NCODE; ++k) {
        float a = 0.f;
        #pragma unroll
        for (int j = 0; j < 64; ++j) a = fmaf(w[j], w[j + k], a);
        acc[k] = a;
    }

    #pragma unroll
    for (int k = 0; k <= NCODE; ++k) {
        acc[k] += __shfl_xor(acc[k], 1, 64);
        acc[k] += __shfl_xor(acc[k], 2, 64);
    }

    // Lane s stores lags [8s, 8s+8) (s==3 also stores lag 32). Static reg
    // indices per branch (rule #20); same-s lanes store consecutive g ->
    // coalesced within each lag plane.
    if (s == 0) {
        #pragma unroll
        for (int q = 0; q < 8; ++q) B[(size_t)q * NG + g] = acc[q];
    } else if (s == 1) {
        #pragma unroll
        for (int q = 0; q < 8; ++q) B[(size_t)(8 + q) * NG + g] = acc[8 + q];
    } else if (s == 2) {
        #pragma unroll
        for (int q = 0; q < 8; ++q) B[(size_t)(16 + q) * NG + g] = acc[16 + q];
    } else {
        #pragma unroll
        for (int q = 0; q < 9; ++q) B[(size_t)(24 + q) * NG + g] = acc[24 + q];
    }
}

// ---------------------------------------------------------------------------
// Pass 2: per frame, corr[k] = sum of 4 block products + wrap/tail correction
//   corr[f,k] = F_k + sum_{j<k} u[32-k+j] * (a[j] - c[j])
//   a = x[o .. o+32), u = x[o+992 .. o+1024), c = x[o+1024 .. o+1056)
// then fully-unrolled Levinson-Durbin, float4 stores.
// ---------------------------------------------------------------------------
__global__ __launch_bounds__(256) void assemble_levinson_kernel(const float* __restrict__ in,
                                                                const float* __restrict__ B,
                                                                float* __restrict__ out) {
    const int t = blockIdx.x * 256 + threadIdx.x;
    if (t >= NFR_TOT) return;
    const int b = t / NFRAMES;
    const int f = t - b * NFRAMES;
    const float* row = in + (size_t)b * T_LEN;
    const int o = f * STRIDE;

    float F[NCODE + 1];
    #pragma unroll
    for (int k = 0; k <= NCODE; ++k) F[k] = 0.f;

    #pragma unroll
    for (int d = 0; d < 4; ++d) {
        const int i = f + d;
        if (i < NBLK) {                 // blocks past the data are all-zero
            const float* Bp = B + ((size_t)b * NBLK + i);
            #pragma unroll
            for (int k = 0; k <= NCODE; ++k) F[k] += Bp[(size_t)k * NG];
        }
    }

    float a[32], u[32], cx[32];
    auto ld4g = [&](int pos, float* dst) {   // pos is a multiple of 4
        float4 v = make_float4(0.f, 0.f, 0.f, 0.f);
        if (pos < T_LEN) v = *reinterpret_cast<const float4*>(row + pos);
        dst[0] = v.x; dst[1] = v.y; dst[2] = v.z; dst[3] = v.w;
    };
    #pragma unroll
    for (int q = 0; q < 8; ++q) ld4g(o + 4 * q,        &a[4 * q]);
    #pragma unroll
    for (int q = 0; q < 8; ++q) ld4g(o + 992 + 4 * q,  &u[4 * q]);
    #pragma unroll
    for (int q = 0; q < 8; ++q) ld4g(o + 1024 + 4 * q, &cx[4 * q]);

    float dd[32];
    #pragma unroll
    for (int j = 0; j < 32; ++j) dd[j] = a[j] - cx[j];

    float corr[NCODE + 1];
    corr[0] = F[0];
    #pragma unroll
    for (int k = 1; k <= NCODE; ++k) {
        float acc2 = F[k];
        #pragma unroll
        for (int j = 0; j < k; ++j) acc2 = fmaf(u[32 - k + j], dd[j], acc2);
        corr[k] = acc2;
    }

    // Levinson-Durbin (verified in r1/r2), fully unrolled -> registers only.
    const float eps = 1e-7f;
    float sol[NCODE + 1];
    const float c0 = fmaxf(corr[0], eps);
    sol[0] = 1.0f;
    sol[1] = -corr[1] / c0;
    float extra = fmaf(corr[1], sol[1], corr[0]);

    #pragma unroll
    for (int k = 1; k < NCODE; ++k) {
        float dot = 0.f;
        #pragma unroll
        for (int i = 0; i <= k; ++i) dot = fmaf(sol[i], corr[k + 1 - i], dot);
        const float lam = -dot / fmaxf(extra, eps);

        float ns[NCODE + 1];
        #pragma unroll
        for (int j = 0; j <= k + 1; ++j) {
            const float av  = (j <= k) ? sol[j] : 0.f;
            const float rev = (j >= 1) ? sol[k + 1 - j] : 0.f;
            ns[j] = fmaf(lam, rev, av);
        }
        #pragma unroll
        for (int j = 0; j <= k + 1; ++j) sol[j] = ns[j];

        extra = (1.f - lam * lam) * extra;
    }

    float* op = out + (size_t)t * NCODE;
    #pragma unroll
    for (int i = 0; i < 8; ++i) {
        *reinterpret_cast<float4*>(op + 4 * i) =
            make_float4(sol[4 * i + 1], sol[4 * i + 2],
                        sol[4 * i + 3], sol[4 * i + 4]);
    }
}

// ---------------------------------------------------------------------------
extern "C" void kernel_launch(void* const* d_in, const int* in_sizes, int n_in,
                              void* d_out, int out_size, void* d_ws, size_t ws_size,
                              hipStream_t stream) {
    const float* in = (const float*)d_in[0];
    float* out      = (float*)d_out;
    float* B        = (float*)d_ws;   // 33 * 65536 * 4 B = 8.65 MB

    blockprod_kernel<<<NG * 4 / 256, 256, 0, stream>>>(in, B);        // 1024 blocks
    assemble_levinson_kernel<<<(NFR_TOT + 255) / 256, 256, 0, stream>>>(in, B, out);
}